// Round 1
// baseline (1488.142 us; speedup 1.0000x reference)
//
#include <hip/hip_runtime.h>
#include <cstdint>
#include <cstddef>

typedef __bf16 bf16x8 __attribute__((ext_vector_type(8)));
typedef float  f32x4  __attribute__((ext_vector_type(4)));

#define MFMA16(a,b,c) __builtin_amdgcn_mfma_f32_16x16x32_bf16((a),(b),(c),0,0,0)

// LDS-only barrier for the per-step h double-buffer handoff; full drain only
// at publish points.
#define BAR_LGKM() __asm__ volatile("s_waitcnt lgkmcnt(0)\n\ts_barrier" ::: "memory")
#define BAR_FULL() __asm__ volatile("s_waitcnt vmcnt(0) lgkmcnt(0)\n\ts_barrier" ::: "memory")

#define L2E  1.4426950408889634f   // log2(e)
#define L2E2 2.8853900817779268f   // 2*log2(e)

// Problem: B=256, T=512, D=H=128, 3H=384. x/out batch stride = 65536 elems.
// 32 blocks: 0..15 layer 0 (producer), 16..31 layer 1 (consumer, lagged).
// h0 crosses XCDs via nt stores/loads + per-pair agent-scope flags.
//
// K-split design: per step, recurrent MFMAs are h·U only (K=128, 4-deep
// chains, C-init = xp_t held in registers); xp_{t+1} = x_{t+1}·W is computed
// the same step as an independent MFMA group (fills the pipe during barrier/
// epilogue latency). x/h0 A-fragments are loaded per-lane directly from
// global (row l15, cols quad*8+kt*32; 16x128B segments per kt, coalescible;
// wave-redundant but L2-absorbed / nt). LDS holds ONLY h (2 x 16 x 136 bf16).
// Weights/biases pre-scaled by log2e (z,r) / 2log2e (h) -> epilogue uses raw
// v_exp (2^x) with free neg modifiers.

// ---------------------------------------------------------------------------
// prep_frags: B-frag layout identical to previous version:
// elem offset = ((ct*8+kt)*64+lane)*8 + j; ct 0..23 (z 0-7, r 8-15, h 16-23);
// kt 0..3 -> W rows kt*32+quad*8, kt 4..7 -> U rows (same -128).
// NEW: values pre-scaled (L2E for z/r cols, L2E2 for h cols).
// ---------------------------------------------------------------------------
__global__ void prep_frags(const float* __restrict__ W0, const float* __restrict__ U0,
                           const float* __restrict__ W1, const float* __restrict__ U1,
                           __bf16* __restrict__ frags, int* __restrict__ flags)
{
    if (blockIdx.x == 0 && threadIdx.x < 16) flags[threadIdx.x * 16] = 0;
    int id = blockIdx.x * 512 + threadIdx.x;      // 0..24575
    int layer = id / 12288;
    int r     = id % 12288;                       // (ct*8+kt)*64 + lane
    int lane = r & 63;
    int ctkt = r >> 6;                            // 0..191
    int kt = ctkt & 7;
    int ct = ctkt >> 3;
    const float* Wsrc = layer ? W1 : W0;
    const float* Usrc = layer ? U1 : U0;
    int n  = ct * 16 + (lane & 15);
    int k0 = kt * 32 + (lane >> 4) * 8;           // never straddles 128
    const float* src = (k0 < 128) ? (Wsrc + (size_t)k0 * 384)
                                  : (Usrc + (size_t)(k0 - 128) * 384);
    const float s = (ct < 16) ? L2E : L2E2;       // z,r vs h columns
    __bf16* dst = frags + (size_t)layer * 98304 + (size_t)r * 8;
#pragma unroll
    for (int j = 0; j < 8; j++)
        dst[j] = (__bf16)(src[(size_t)j * 384 + n] * s);
}

// ---------------------------------------------------------------------------
// gru_pipe: 512 threads (8 waves), 16 batch rows/block. Wave w owns hidden
// col j=16w+l15 for all 3 gates. Producer publishes flag=t every 4th step
// after a FULL drain; consumer gates its t+2 prefetch on flag >= t+3.
// h0 may alias out (small-ws fallback): consumer reads slot t+2 strictly
// before overwriting slot t. No __restrict__ on x/h0/out.
// ---------------------------------------------------------------------------
__global__ __launch_bounds__(512, 2) void gru_pipe(
    const float* x, const __bf16* __restrict__ frags,
    const float* __restrict__ b0, const float* __restrict__ b1,
    float* h0, float* out, int* flags)
{
    __shared__ __align__(16) __bf16 hb[2][16 * 136];   // h only, 8.7 KB

    const int tid  = threadIdx.x;
    const int wave = tid >> 6, lane = tid & 63;
    const int l15  = lane & 15, quad = lane >> 4;
    const int pair  = blockIdx.x & 15;
    const int layer = blockIdx.x >> 4;
    const int B0 = pair * 16;
    int* const flagp = flags + pair * 16;          // one 64B line per pair

    const __bf16* Bf  = frags + (size_t)layer * 98304;
    const float* bias = layer ? b1 : b0;
    const float* xin  = layer ? h0 : x;
    float*       hout = layer ? out : h0;

    // persistent frags: W (xp path, kt 0..3) and U (recurrent, kt 4..7)
    bf16x8 bw[3][4], bu[3][4];
#pragma unroll
    for (int g = 0; g < 3; g++) {
        int ct = 8 * g + wave;
#pragma unroll
        for (int kt = 0; kt < 4; kt++) {
            bw[g][kt] = *(const bf16x8*)(Bf + (size_t)((ct * 8 + kt) * 64 + lane) * 8);
            bu[g][kt] = *(const bf16x8*)(Bf + (size_t)((ct * 8 + kt + 4) * 64 + lane) * 8);
        }
    }

    const int j = wave * 16 + l15;
    const float bz  = (bias[j]       + bias[384 + j]) * L2E;
    const float br  = (bias[128 + j] + bias[512 + j]) * L2E;
    const float bxh = bias[256 + j] * L2E2;
    const float brh = bias[640 + j] * L2E2;

    // per-lane direct A-fragment source: row B0+l15, col base quad*8
    const float* px = xin + (size_t)(B0 + l15) * 65536 + quad * 8;
    const size_t obase = (size_t)(B0 + quad * 4) * 65536 + j;

    int known = 0;
    if (layer) {
        while (known < 2) {
            __builtin_amdgcn_s_sleep(4);
            known = __hip_atomic_load(flagp, __ATOMIC_RELAXED,
                                      __HIP_MEMORY_SCOPE_AGENT);
        }
    }

    f32x4 raw[8];
    auto issue_raw = [&](const float* P) {
#pragma unroll
        for (int kt = 0; kt < 4; kt++) {
            if (layer) {
                raw[2 * kt]     = __builtin_nontemporal_load((const f32x4*)(P + kt * 32));
                raw[2 * kt + 1] = __builtin_nontemporal_load((const f32x4*)(P + kt * 32 + 4));
            } else {
                raw[2 * kt]     = *(const f32x4*)(P + kt * 32);
                raw[2 * kt + 1] = *(const f32x4*)(P + kt * 32 + 4);
            }
        }
    };

    const f32x4 zv = {0.f, 0.f, 0.f, 0.f};

    // ---- prologue: xp_0 from x_0; preload x_1; zero h buffer 0 ----
    issue_raw(px);                                  // x_0
    for (int i = tid; i < 544; i += 512)            // 16*136*2B = 544 * 8B
        ((uint64_t*)hb[0])[i] = 0ull;

    f32x4 cz = zv, cr = zv, ch = zv;                // xp carry (= xp_t)
#pragma unroll
    for (int kt = 0; kt < 4; kt++) {
        bf16x8 a;
#pragma unroll
        for (int e = 0; e < 4; e++) {
            a[e]     = (__bf16)raw[2 * kt][e];
            a[4 + e] = (__bf16)raw[2 * kt + 1][e];
        }
        cz = MFMA16(a, bw[0][kt], cz);
        cr = MFMA16(a, bw[1][kt], cr);
        ch = MFMA16(a, bw[2][kt], ch);
    }
    issue_raw(px + 128);                            // x_1
    float hold[4] = {0.f, 0.f, 0.f, 0.f};
    __syncthreads();

    const int hbase = l15 * 136 + quad * 8;

    for (int t = 0; t < 512; t++) {
        const int cur = t & 1, nxt = cur ^ 1;

        if (layer) {                                // gate the t+2 prefetch
            int need = t + 3; if (need > 512) need = 512;
            while (known < need) {
                __builtin_amdgcn_s_sleep(4);
                known = __hip_atomic_load(flagp, __ATOMIC_RELAXED,
                                          __HIP_MEMORY_SCOPE_AGENT);
            }
        }

        // recurrent path: h_{t-1} frags from LDS, C-init = xp_t (registers)
        bf16x8 Ah[4];
#pragma unroll
        for (int kt = 0; kt < 4; kt++)
            Ah[kt] = *(const bf16x8*)&hb[cur][hbase + kt * 32];

        f32x4 az = cz, ar = cr, ah = zv;
#pragma unroll
        for (int kt = 0; kt < 4; kt++) {
            az = MFMA16(Ah[kt], bu[0][kt], az);
            ar = MFMA16(Ah[kt], bu[1][kt], ar);
            ah = MFMA16(Ah[kt], bu[2][kt], ah);
        }

        // xp_{t+1} = x_{t+1}*W : independent MFMA group, fills pipe slack
        f32x4 nz = zv, nr = zv, nh = zv;
#pragma unroll
        for (int kt = 0; kt < 4; kt++) {
            bf16x8 a;
#pragma unroll
            for (int e = 0; e < 4; e++) {
                a[e]     = (__bf16)raw[2 * kt][e];
                a[4 + e] = (__bf16)raw[2 * kt + 1][e];
            }
            nz = MFMA16(a, bw[0][kt], nz);
            nr = MFMA16(a, bw[1][kt], nr);
            nh = MFMA16(a, bw[2][kt], nh);
        }

        const int t2 = (t < 510) ? (t + 2) : 511;
        const float* p2 = px + (size_t)t2 * 128;

        // epilogue: everything pre-scaled by log2e/2log2e -> raw 2^x
        float hnew[4];
#pragma unroll
        for (int r = 0; r < 4; r++) {
            float z  = __builtin_amdgcn_rcpf(
                           1.f + __builtin_amdgcn_exp2f(-(az[r] + bz)));
            float rg = __builtin_amdgcn_rcpf(
                           1.f + __builtin_amdgcn_exp2f(-(ar[r] + br)));
            float hp = (ch[r] + bxh) + rg * (ah[r] + brh);
            float e2 = __builtin_amdgcn_exp2f(hp);
            float th = 1.f - 2.f * __builtin_amdgcn_rcpf(e2 + 1.f);
            hnew[r] = th + z * (hold[r] - th);
            hold[r] = hnew[r];
        }

        // h_t -> LDS next buffer (cols are the only exchange now)
#pragma unroll
        for (int r = 0; r < 4; r++)
            hb[nxt][(quad * 4 + r) * 136 + j] = (__bf16)hnew[r];

        // barrier: lgkm-only normally; full drain + publish every 4th step.
        // On publish steps the prefetch is issued AFTER the drain so
        // vmcnt(0) only covers >=1-step-old stores (~free).
        if (layer == 0 && (t & 3) == 3) {
            BAR_FULL();                 // h0 stores of steps <= t-1 in HBM
            if (tid == 0)
                __hip_atomic_store(flagp, t, __ATOMIC_RELAXED,
                                   __HIP_MEMORY_SCOPE_AGENT);
            issue_raw(p2);
        } else {
            issue_raw(p2);
            BAR_LGKM();
        }

        // h_t -> global (drains during subsequent steps)
        if (layer == 0) {
#pragma unroll
            for (int r = 0; r < 4; r++)
                __builtin_nontemporal_store(hnew[r],
                    hout + obase + (size_t)r * 65536 + (size_t)t * 128);
        } else {
#pragma unroll
            for (int r = 0; r < 4; r++)
                hout[obase + (size_t)r * 65536 + (size_t)t * 128] = hnew[r];
        }

        cz = nz; cr = nr; ch = nh;
    }

    if (layer == 0) {
        BAR_FULL();        // drain final h0 stores (incl. step 511)
        if (tid == 0)
            __hip_atomic_store(flagp, 512, __ATOMIC_RELAXED,
                               __HIP_MEMORY_SCOPE_AGENT);
    }
}

// ---------------------------------------------------------------------------
extern "C" void kernel_launch(void* const* d_in, const int* in_sizes, int n_in,
                              void* d_out, int out_size, void* d_ws, size_t ws_size,
                              hipStream_t stream)
{
    const float* x  = (const float*)d_in[0];
    const float* W0 = (const float*)d_in[1];
    const float* U0 = (const float*)d_in[2];
    const float* b0 = (const float*)d_in[3];
    const float* W1 = (const float*)d_in[4];
    const float* U1 = (const float*)d_in[5];
    const float* b1 = (const float*)d_in[6];
    float* out = (float*)d_out;

    char* ws = (char*)d_ws;
    __bf16* frags = (__bf16*)ws;                 // 2 * 98304 bf16 = 393,216 B
    int*    flags = (int*)(ws + 393216);         // 16 pairs x 64 B = 1024 B
    // h0 at ws + 448 KiB if it fits, else alias d_out (pipeline-safe: consumer
    // reads slot t+2 strictly before overwriting slot t).
    float* h0;
    const size_t need = 458752 + 67108864;
    if (ws_size >= need) h0 = (float*)(ws + 458752);
    else                 h0 = out;

    prep_frags<<<48, 512, 0, stream>>>(W0, U0, W1, U1, frags, flags);
    gru_pipe<<<32, 512, 0, stream>>>(x, frags, b0, b1, h0, out, flags);
}

// Round 3
// 1008.486 us; speedup vs baseline: 1.4756x; 1.4756x over previous
//
#include <hip/hip_runtime.h>
#include <cstdint>
#include <cstddef>

typedef __bf16 bf16x8 __attribute__((ext_vector_type(8)));
typedef __bf16 bf16x4 __attribute__((ext_vector_type(4)));
typedef float  f32x4  __attribute__((ext_vector_type(4)));

#define MFMA16(a,b,c) __builtin_amdgcn_mfma_f32_16x16x32_bf16((a),(b),(c),0,0,0)

// LDS-only barrier: the per-step double-buffer handoff needs lgkmcnt(0) only.
// Global stores are drained explicitly at publish points (BAR_FULL).
#define BAR_LGKM() __asm__ volatile("s_waitcnt lgkmcnt(0)\n\ts_barrier" ::: "memory")
#define BAR_FULL() __asm__ volatile("s_waitcnt vmcnt(0) lgkmcnt(0)\n\ts_barrier" ::: "memory")

#define L2E  1.4426950408889634f   // log2(e)
#define L2E2 2.8853900817779268f   // 2*log2(e)

// Problem: B=256, T=512, D=H=128, 3H=384. x/out batch stride = 65536 elems.
// 16 blocks: 0..7 layer 0 (producer), 8..15 layer 1 (consumer, lagged).
// h0 crosses XCDs via nt stores/loads (bypass non-coherent L2s) + per-pair
// agent-scope progress flags (64B-padded).
//
// Round-0 structure (LDS-staged A=[x_t | h_{t-1}], K=256, one barrier/step)
// + TWO independent batch-row groups per block (32 rows/pair): group-B MFMAs
// overlap group-A's epilogue VALU in the same wave (independent recurrences,
// same timestep, one shared barrier). Weights/biases pre-scaled by log2e
// (z,r) / 2log2e (h) -> epilogue uses raw v_exp (2^x).

// ---------------------------------------------------------------------------
// prep_frags: stacked-weight B-frags, K=256 ([W(128) ; U(128)]), + flag init.
// Frag layout (16x16x32): B[k][n], n = lane&15, k = kt*32 + (lane>>4)*8 + j.
// Elem offset = ((ct*8+kt)*64 + lane)*8 + j, ct 0..23 (z:0-7,r:8-15,h:16-23),
// kt 0..7 (kt<4 -> W rows k, kt>=4 -> U rows k-128). Per layer: 98304 bf16.
// Values pre-scaled: L2E for z/r cols (ct<16), L2E2 for h cols (ct>=16).
// ---------------------------------------------------------------------------
__global__ void prep_frags(const float* __restrict__ W0, const float* __restrict__ U0,
                           const float* __restrict__ W1, const float* __restrict__ U1,
                           __bf16* __restrict__ frags, int* __restrict__ flags)
{
    if (blockIdx.x == 0 && threadIdx.x < 16) flags[threadIdx.x * 16] = 0;
    int id = blockIdx.x * 512 + threadIdx.x;      // 0..24575
    int layer = id / 12288;
    int r     = id % 12288;                       // (ct*8+kt)*64 + lane
    int lane = r & 63;
    int ctkt = r >> 6;                            // 0..191
    int kt = ctkt & 7;
    int ct = ctkt >> 3;
    const float* Wsrc = layer ? W1 : W0;
    const float* Usrc = layer ? U1 : U0;
    int n  = ct * 16 + (lane & 15);
    int k0 = kt * 32 + (lane >> 4) * 8;           // never straddles 128
    const float* src = (k0 < 128) ? (Wsrc + (size_t)k0 * 384)
                                  : (Usrc + (size_t)(k0 - 128) * 384);
    const float s = (ct < 16) ? L2E : L2E2;       // z,r vs h columns
    __bf16* dst = frags + (size_t)layer * 98304 + (size_t)r * 8;
#pragma unroll
    for (int j = 0; j < 8; j++)
        dst[j] = (__bf16)(src[(size_t)j * 384 + n] * s);
}

// ---------------------------------------------------------------------------
// gru_pipe: both GRU layers, pipelined across block pairs. Per block: 32
// batch rows (two groups of 16), 512 threads (8 waves, 2/SIMD). Wave w owns
// hidden col j=16w+l15 for all gates, for BOTH groups. A=[x_t | h_{t-1}]
// bf16 K=256, LDS stride 264, double-buffered per group, ONE barrier/step.
// acc per group: z(K256), r(K256), xh(kt0-3), rec_h(kt4-7).
// Producer publishes flag=t every 4th step (t%4==3) after a FULL drain:
// flag F asserts h0 steps 0..F-1 are in HBM. Consumer gates its t+2 prefetch
// on flag >= t+3. h0 may alias out (small-ws fallback): consumer reads slot
// t+2 strictly before overwriting slot t. No __restrict__ on x/h0/out.
// ---------------------------------------------------------------------------
__global__ __launch_bounds__(512, 2) void gru_pipe(
    const float* x, const __bf16* __restrict__ frags,
    const float* __restrict__ b0, const float* __restrict__ b1,
    float* h0, float* out, int* flags)
{
    __shared__ __align__(16) __bf16 ab[2][2][16 * 264];   // [group][buf], 33.8 KB

    const int tid  = threadIdx.x;
    const int wave = tid >> 6, lane = tid & 63;
    const int l15  = lane & 15, quad = lane >> 4;
    const int pair  = blockIdx.x & 7;
    const int layer = blockIdx.x >> 3;
    const int B0 = pair * 32;
    int* const flagp = flags + pair * 16;          // one 64B line per pair

    const __bf16* Bf  = frags + (size_t)layer * 98304;
    const float* bias = layer ? b1 : b0;
    const float* xin  = layer ? h0 : x;
    float*       hout = layer ? out : h0;

    // persistent stacked B-frags: 3 gates x 8 kt = 24 frags
    bf16x8 bfr[3][8];
#pragma unroll
    for (int g = 0; g < 3; g++) {
        int ct = 8 * g + wave;
#pragma unroll
        for (int kt = 0; kt < 8; kt++)
            bfr[g][kt] = *(const bf16x8*)(Bf + (size_t)((ct * 8 + kt) * 64 + lane) * 8);
    }

    const int j = wave * 16 + l15;
    const float bz  = (bias[j]       + bias[384 + j]) * L2E;
    const float br  = (bias[128 + j] + bias[512 + j]) * L2E;
    const float bxh = bias[256 + j] * L2E2;
    const float brh = bias[640 + j] * L2E2;

    // staging map: 512 threads cover 16 rows x 128 cols (4 floats) per group
    const int srow = tid >> 5;
    const int c4   = (tid & 31) * 4;
    const float* pxA = xin + (size_t)(B0 + srow) * 65536 + c4;
    const float* pxB = pxA + (size_t)16 * 65536;
    const int sidx = srow * 264 + c4;

    const size_t obaseA = (size_t)(B0 + quad * 4) * 65536 + j;
    const size_t obaseB = obaseA + (size_t)16 * 65536;

    int known = 0;
    if (layer) {
        while (known < 2) {
            __builtin_amdgcn_s_sleep(4);
            known = __hip_atomic_load(flagp, __ATOMIC_RELAXED,
                                      __HIP_MEMORY_SCOPE_AGENT);
        }
    }

#define LOADX(p) (layer ? __builtin_nontemporal_load((const f32x4*)(p)) \
                        : *(const f32x4*)(p))

    // ---- prologue: stage step-0 input, zero h-parts, preload step 1 ----
    f32x4 vcA = LOADX(pxA), vcB = LOADX(pxB);
    {
        bf16x4 hv;
        hv.x = (__bf16)vcA[0]; hv.y = (__bf16)vcA[1];
        hv.z = (__bf16)vcA[2]; hv.w = (__bf16)vcA[3];
        *(bf16x4*)&ab[0][0][sidx] = hv;
        hv.x = (__bf16)vcB[0]; hv.y = (__bf16)vcB[1];
        hv.z = (__bf16)vcB[2]; hv.w = (__bf16)vcB[3];
        *(bf16x4*)&ab[1][0][sidx] = hv;
    }
    if (tid < 256) {
        int row = tid >> 4, seg = tid & 15;
        *(uint4*)&ab[0][0][row * 264 + 128 + seg * 8] = make_uint4(0, 0, 0, 0);
        *(uint4*)&ab[1][0][row * 264 + 128 + seg * 8] = make_uint4(0, 0, 0, 0);
    }
    __syncthreads();
    vcA = LOADX(pxA + 128);
    vcB = LOADX(pxB + 128);

    float holdA[4] = {0.f, 0.f, 0.f, 0.f};
    float holdB[4] = {0.f, 0.f, 0.f, 0.f};
    const int abase = l15 * 264 + quad * 8;

    for (int t = 0; t < 512; t++) {
        const int cur = t & 1, nxt = cur ^ 1;

        if (layer) {                                // gate the t+2 prefetch
            int need = t + 3; if (need > 512) need = 512;
            while (known < need) {
                __builtin_amdgcn_s_sleep(4);
                known = __hip_atomic_load(flagp, __ATOMIC_RELAXED,
                                          __HIP_MEMORY_SCOPE_AGENT);
            }
        }
        const int t2 = (t < 510) ? (t + 2) : 511;
        f32x4 vnA = LOADX(pxA + (size_t)t2 * 128);
        f32x4 vnB = LOADX(pxB + (size_t)t2 * 128);

        // A-frags: 8 K-slabs per group (x: kt 0..3, h: kt 4..7)
        bf16x8 A0[8], A1[8];
#pragma unroll
        for (int kt = 0; kt < 8; kt++) {
            A0[kt] = *(const bf16x8*)&ab[0][cur][abase + kt * 32];
            A1[kt] = *(const bf16x8*)&ab[1][cur][abase + kt * 32];
        }

        f32x4 aA[4] = {{0,0,0,0},{0,0,0,0},{0,0,0,0},{0,0,0,0}};
        f32x4 aB[4] = {{0,0,0,0},{0,0,0,0},{0,0,0,0},{0,0,0,0}};
#pragma unroll
        for (int kt = 0; kt < 8; kt++) {
            aA[0] = MFMA16(A0[kt], bfr[0][kt], aA[0]);           // z (merged)
            aA[1] = MFMA16(A0[kt], bfr[1][kt], aA[1]);           // r (merged)
            aA[(kt < 4) ? 2 : 3] = MFMA16(A0[kt], bfr[2][kt], aA[(kt < 4) ? 2 : 3]);
        }
#pragma unroll
        for (int kt = 0; kt < 8; kt++) {
            aB[0] = MFMA16(A1[kt], bfr[0][kt], aB[0]);
            aB[1] = MFMA16(A1[kt], bfr[1][kt], aB[1]);
            aB[(kt < 4) ? 2 : 3] = MFMA16(A1[kt], bfr[2][kt], aB[(kt < 4) ? 2 : 3]);
        }

        // stage step t+1 input for both groups (vc from previous prefetch);
        // independent of the MFMAs above -> overlaps their pipe latency
        {
            bf16x4 hv;
            hv.x = (__bf16)vcA[0]; hv.y = (__bf16)vcA[1];
            hv.z = (__bf16)vcA[2]; hv.w = (__bf16)vcA[3];
            *(bf16x4*)&ab[0][nxt][sidx] = hv;
            hv.x = (__bf16)vcB[0]; hv.y = (__bf16)vcB[1];
            hv.z = (__bf16)vcB[2]; hv.w = (__bf16)vcB[3];
            *(bf16x4*)&ab[1][nxt][sidx] = hv;
        }

        // epilogue A (VALU overlaps group-B MFMAs still in the matrix pipe)
        float hnA[4], hnB[4];
#pragma unroll
        for (int r = 0; r < 4; r++) {
            float z  = __builtin_amdgcn_rcpf(
                           1.f + __builtin_amdgcn_exp2f(-(aA[0][r] + bz)));
            float rg = __builtin_amdgcn_rcpf(
                           1.f + __builtin_amdgcn_exp2f(-(aA[1][r] + br)));
            float hp = (aA[2][r] + bxh) + rg * (aA[3][r] + brh);
            float e2 = __builtin_amdgcn_exp2f(hp);
            float th = 1.f - 2.f * __builtin_amdgcn_rcpf(e2 + 1.f);
            hnA[r] = th + z * (holdA[r] - th);
            holdA[r] = hnA[r];
            ab[0][nxt][(quad * 4 + r) * 264 + 128 + j] = (__bf16)hnA[r];
        }
#pragma unroll
        for (int r = 0; r < 4; r++) {
            float z  = __builtin_amdgcn_rcpf(
                           1.f + __builtin_amdgcn_exp2f(-(aB[0][r] + bz)));
            float rg = __builtin_amdgcn_rcpf(
                           1.f + __builtin_amdgcn_exp2f(-(aB[1][r] + br)));
            float hp = (aB[2][r] + bxh) + rg * (aB[3][r] + brh);
            float e2 = __builtin_amdgcn_exp2f(hp);
            float th = 1.f - 2.f * __builtin_amdgcn_rcpf(e2 + 1.f);
            hnB[r] = th + z * (holdB[r] - th);
            holdB[r] = hnB[r];
            ab[1][nxt][(quad * 4 + r) * 264 + 128 + j] = (__bf16)hnB[r];
        }

        // barrier: lgkm-only normally; full drain + publish every 4th step
        if (layer == 0 && (t & 3) == 3) {
            BAR_FULL();                 // h0 stores of steps <= t-1 in HBM
            if (tid == 0)
                __hip_atomic_store(flagp, t, __ATOMIC_RELAXED,
                                   __HIP_MEMORY_SCOPE_AGENT);
        } else {
            BAR_LGKM();
        }

        // h_t -> global (drains during subsequent steps)
        if (layer == 0) {
#pragma unroll
            for (int r = 0; r < 4; r++) {
                __builtin_nontemporal_store(hnA[r],
                    hout + obaseA + (size_t)r * 65536 + (size_t)t * 128);
                __builtin_nontemporal_store(hnB[r],
                    hout + obaseB + (size_t)r * 65536 + (size_t)t * 128);
            }
        } else {
#pragma unroll
            for (int r = 0; r < 4; r++) {
                hout[obaseA + (size_t)r * 65536 + (size_t)t * 128] = hnA[r];
                hout[obaseB + (size_t)r * 65536 + (size_t)t * 128] = hnB[r];
            }
        }

        vcA = vnA; vcB = vnB;
    }

    if (layer == 0) {
        BAR_FULL();        // drain final h0 stores (incl. step 511)
        if (tid == 0)
            __hip_atomic_store(flagp, 512, __ATOMIC_RELAXED,
                               __HIP_MEMORY_SCOPE_AGENT);
    }
#undef LOADX
}

// ---------------------------------------------------------------------------
extern "C" void kernel_launch(void* const* d_in, const int* in_sizes, int n_in,
                              void* d_out, int out_size, void* d_ws, size_t ws_size,
                              hipStream_t stream)
{
    const float* x  = (const float*)d_in[0];
    const float* W0 = (const float*)d_in[1];
    const float* U0 = (const float*)d_in[2];
    const float* b0 = (const float*)d_in[3];
    const float* W1 = (const float*)d_in[4];
    const float* U1 = (const float*)d_in[5];
    const float* b1 = (const float*)d_in[6];
    float* out = (float*)d_out;

    char* ws = (char*)d_ws;
    __bf16* frags = (__bf16*)ws;                 // 2 * 98304 bf16 = 393,216 B
    int*    flags = (int*)(ws + 393216);         // 16 x 64 B = 1024 B
    // h0 at ws + 448 KiB if it fits, else alias d_out (pipeline-safe: consumer
    // reads slot t+2 strictly before overwriting slot t).
    float* h0;
    const size_t need = 458752 + 67108864;
    if (ws_size >= need) h0 = (float*)(ws + 458752);
    else                 h0 = out;

    prep_frags<<<48, 512, 0, stream>>>(W0, U0, W1, U1, frags, flags);
    gru_pipe<<<16, 512, 0, stream>>>(x, frags, b0, b1, h0, out, flags);
}

// Round 4
// 576.144 us; speedup vs baseline: 2.5829x; 1.7504x over previous
//
#include <hip/hip_runtime.h>
#include <cstdint>
#include <cstddef>

typedef __bf16 bf16x8 __attribute__((ext_vector_type(8)));
typedef __bf16 bf16x4 __attribute__((ext_vector_type(4)));
typedef float  f32x4  __attribute__((ext_vector_type(4)));

#define MFMA16(a,b,c) __builtin_amdgcn_mfma_f32_16x16x32_bf16((a),(b),(c),0,0,0)

// LDS-only barrier: the per-step double-buffer handoff needs lgkmcnt(0) only.
// Global stores are drained explicitly at publish points (BAR_FULL).
#define BAR_LGKM() __asm__ volatile("s_waitcnt lgkmcnt(0)\n\ts_barrier" ::: "memory")
#define BAR_FULL() __asm__ volatile("s_waitcnt vmcnt(0) lgkmcnt(0)\n\ts_barrier" ::: "memory")

#define L2E  1.4426950408889634f   // log2(e)
#define L2E2 2.8853900817779268f   // 2*log2(e)

// Problem: B=256, T=512, D=H=128, 3H=384. x/out batch stride = 65536 elems.
// 32 blocks (round-0 structure, measured best): 0..15 layer 0 (producer),
// 16..31 layer 1 (consumer, lagged 2+ steps). h0 crosses XCDs via nt
// stores/loads + per-pair agent-scope progress flags (64B-padded lines).
//
// Round-4 change: B-frags were NOT register-resident before (VGPR_Count=80
// proves the compiler sank the 24 loop-invariant weight loads into the
// K-loop -> ~24 L2-hit global loads + addressing per wave per step). Pin
// them with an identity asm so the loads cannot be rematerialized; raise
// the VGPR cap via __launch_bounds__(512,2) (2 waves/SIMD -> cap 256).
// Weights/biases pre-scaled by log2e (z,r) / 2log2e (h) -> epilogue uses
// raw v_exp (2^x) (validated in round 3, absmax 0.0039 unchanged).

// ---------------------------------------------------------------------------
// prep_frags: stacked-weight B-frags, K=256 ([W(128) ; U(128)]), + flag init.
// Frag layout (16x16x32): B[k][n], n = lane&15, k = kt*32 + (lane>>4)*8 + j.
// Elem offset = ((ct*8+kt)*64 + lane)*8 + j, ct 0..23 (z:0-7,r:8-15,h:16-23),
// kt 0..7 (kt<4 -> W rows k, kt>=4 -> U rows k-128). Per layer: 98304 bf16.
// Values pre-scaled: L2E for z/r cols (ct<16), L2E2 for h cols (ct>=16).
// ---------------------------------------------------------------------------
__global__ void prep_frags(const float* __restrict__ W0, const float* __restrict__ U0,
                           const float* __restrict__ W1, const float* __restrict__ U1,
                           __bf16* __restrict__ frags, int* __restrict__ flags)
{
    if (blockIdx.x == 0 && threadIdx.x < 16) flags[threadIdx.x * 16] = 0;
    int id = blockIdx.x * 512 + threadIdx.x;      // 0..24575
    int layer = id / 12288;
    int r     = id % 12288;                       // (ct*8+kt)*64 + lane
    int lane = r & 63;
    int ctkt = r >> 6;                            // 0..191
    int kt = ctkt & 7;
    int ct = ctkt >> 3;
    const float* Wsrc = layer ? W1 : W0;
    const float* Usrc = layer ? U1 : U0;
    int n  = ct * 16 + (lane & 15);
    int k0 = kt * 32 + (lane >> 4) * 8;           // never straddles 128
    const float* src = (k0 < 128) ? (Wsrc + (size_t)k0 * 384)
                                  : (Usrc + (size_t)(k0 - 128) * 384);
    const float s = (ct < 16) ? L2E : L2E2;       // z,r vs h columns
    __bf16* dst = frags + (size_t)layer * 98304 + (size_t)r * 8;
#pragma unroll
    for (int j = 0; j < 8; j++)
        dst[j] = (__bf16)(src[(size_t)j * 384 + n] * s);
}

// ---------------------------------------------------------------------------
// gru_pipe: both GRU layers, pipelined across block pairs. Per block: 16
// batch rows, 512 threads (8 waves, 2/SIMD). Wave w owns hidden col
// j=16w+l15 for all gates. A=[x_t | h_{t-1}] bf16 K=256, LDS stride 264,
// double-buffered, ONE lgkm-only barrier/step. acc: z(K256), r(K256),
// xh(kt0-3), rec_h(kt4-7) — reset_after multiplies r into recurrent only.
// Producer publishes flag=t every 4th step (t%4==3) after a FULL drain
// barrier: flag F asserts h0 steps 0..F-1 are in HBM. Consumer gates its
// t+2 prefetch on flag >= t+3. h0 may alias out (small-ws fallback):
// consumer reads slot t+2 strictly before overwriting slot t.
// No __restrict__ on x/h0/out.
// ---------------------------------------------------------------------------
__global__ __launch_bounds__(512, 2) void gru_pipe(
    const float* x, const __bf16* __restrict__ frags,
    const float* __restrict__ b0, const float* __restrict__ b1,
    float* h0, float* out, int* flags)
{
    __shared__ __align__(16) __bf16 ab[2][16 * 264];

    const int tid  = threadIdx.x;
    const int wave = tid >> 6, lane = tid & 63;
    const int l15  = lane & 15, quad = lane >> 4;
    const int pair  = blockIdx.x & 15;
    const int layer = blockIdx.x >> 4;
    const int B0 = pair * 16;
    int* const flagp = flags + pair * 16;          // one 64B line per pair

    const __bf16* Bf  = frags + (size_t)layer * 98304;
    const float* bias = layer ? b1 : b0;
    const float* xin  = layer ? h0 : x;
    float*       hout = layer ? out : h0;

    // persistent stacked B-frags: 3 gates x 8 kt = 24 frags (96 VGPR).
    // The asm pin makes the identity-asm the value's producer -> the loads
    // cannot be sunk/rematerialized inside the t-loop (VGPR_Count must
    // rise to >=160; 80 before = reload-per-step).
    bf16x8 bfr[3][8];
#pragma unroll
    for (int g = 0; g < 3; g++) {
        int ct = 8 * g + wave;
#pragma unroll
        for (int kt = 0; kt < 8; kt++) {
            bfr[g][kt] = *(const bf16x8*)(Bf + (size_t)((ct * 8 + kt) * 64 + lane) * 8);
            __asm__ volatile("" : "+v"(bfr[g][kt]));
        }
    }

    const int j = wave * 16 + l15;
    const float bz  = (bias[j]       + bias[384 + j]) * L2E;
    const float br  = (bias[128 + j] + bias[512 + j]) * L2E;
    const float bxh = bias[256 + j] * L2E2;
    const float brh = bias[640 + j] * L2E2;

    // staging map: 512 threads cover 16 rows x 128 cols (4 floats each)
    const int srow = tid >> 5;
    const int c4   = (tid & 31) * 4;
    const float* px = xin + (size_t)(B0 + srow) * 65536 + c4;
    const int sidx = srow * 264 + c4;

    const size_t obase = (size_t)(B0 + quad * 4) * 65536 + j;

    int known = 0;
    if (layer) {
        while (known < 2) {
            __builtin_amdgcn_s_sleep(4);
            known = __hip_atomic_load(flagp, __ATOMIC_RELAXED,
                                      __HIP_MEMORY_SCOPE_AGENT);
        }
    }

    // ---- prologue: stage step-0 input, zero h-part, preload step 1 ----
    f32x4 vc = layer ? __builtin_nontemporal_load((const f32x4*)px)
                     : *(const f32x4*)px;
    {
        bf16x4 hv;
        hv.x = (__bf16)vc[0]; hv.y = (__bf16)vc[1];
        hv.z = (__bf16)vc[2]; hv.w = (__bf16)vc[3];
        *(bf16x4*)&ab[0][sidx] = hv;
    }
    if (tid < 256) {
        int row = tid >> 4, seg = tid & 15;
        *(uint4*)&ab[0][row * 264 + 128 + seg * 8] = make_uint4(0, 0, 0, 0);
    }
    __syncthreads();
    vc = layer ? __builtin_nontemporal_load((const f32x4*)(px + 128))
               : *(const f32x4*)(px + 128);

    float hold[4] = {0.f, 0.f, 0.f, 0.f};
    const int abase = l15 * 264 + quad * 8;

    for (int t = 0; t < 512; t++) {
        const int cur = t & 1, nxt = cur ^ 1;

        if (layer) {                                // gate the t+2 prefetch
            int need = t + 3; if (need > 512) need = 512;
            while (known < need) {
                __builtin_amdgcn_s_sleep(4);
                known = __hip_atomic_load(flagp, __ATOMIC_RELAXED,
                                          __HIP_MEMORY_SCOPE_AGENT);
            }
        }
        const int t2 = (t < 510) ? (t + 2) : 511;
        f32x4 vn = layer
            ? __builtin_nontemporal_load((const f32x4*)(px + (size_t)t2 * 128))
            : *(const f32x4*)(px + (size_t)t2 * 128);

        // A-frags: 8 K-slabs (x: kt 0..3, h: kt 4..7)
        bf16x8 A[8];
#pragma unroll
        for (int kt = 0; kt < 8; kt++)
            A[kt] = *(const bf16x8*)&ab[cur][abase + kt * 32];

        f32x4 acc[4] = {{0,0,0,0},{0,0,0,0},{0,0,0,0},{0,0,0,0}};
        __builtin_amdgcn_s_setprio(1);
#pragma unroll
        for (int kt = 0; kt < 8; kt++) {
            acc[0] = MFMA16(A[kt], bfr[0][kt], acc[0]);          // z (merged)
            acc[1] = MFMA16(A[kt], bfr[1][kt], acc[1]);          // r (merged)
            acc[(kt < 4) ? 2 : 3] = MFMA16(A[kt], bfr[2][kt], acc[(kt < 4) ? 2 : 3]);
        }
        __builtin_amdgcn_s_setprio(0);

        // epilogue: everything pre-scaled by log2e/2log2e -> raw 2^x
        float hnew[4];
#pragma unroll
        for (int r = 0; r < 4; r++) {
            float z  = __builtin_amdgcn_rcpf(
                           1.f + __builtin_amdgcn_exp2f(-(acc[0][r] + bz)));
            float rg = __builtin_amdgcn_rcpf(
                           1.f + __builtin_amdgcn_exp2f(-(acc[1][r] + br)));
            float hp = (acc[2][r] + bxh) + rg * (acc[3][r] + brh);
            float e2 = __builtin_amdgcn_exp2f(hp);
            float th = 1.f - 2.f * __builtin_amdgcn_rcpf(e2 + 1.f);
            hnew[r] = th + z * (hold[r] - th);
            hold[r] = hnew[r];
        }

        // stage step t+1 input (vc from previous prefetch)
        {
            bf16x4 hv;
            hv.x = (__bf16)vc[0]; hv.y = (__bf16)vc[1];
            hv.z = (__bf16)vc[2]; hv.w = (__bf16)vc[3];
            *(bf16x4*)&ab[nxt][sidx] = hv;
        }
        // h_t -> LDS h-part (cols 128..255)
#pragma unroll
        for (int r = 0; r < 4; r++)
            ab[nxt][(quad * 4 + r) * 264 + 128 + j] = (__bf16)hnew[r];

        // barrier: lgkm-only normally; full drain + publish every 4th step
        if (layer == 0 && (t & 3) == 3) {
            BAR_FULL();                 // h0 stores of steps <= t-1 in HBM
            if (tid == 0)
                __hip_atomic_store(flagp, t, __ATOMIC_RELAXED,
                                   __HIP_MEMORY_SCOPE_AGENT);
        } else {
            BAR_LGKM();
        }

        // h_t -> global (drains during subsequent steps)
        if (layer == 0) {
#pragma unroll
            for (int r = 0; r < 4; r++)
                __builtin_nontemporal_store(hnew[r],
                    hout + obase + (size_t)r * 65536 + (size_t)t * 128);
        } else {
#pragma unroll
            for (int r = 0; r < 4; r++)
                hout[obase + (size_t)r * 65536 + (size_t)t * 128] = hnew[r];
        }

        vc = vn;
    }

    if (layer == 0) {
        BAR_FULL();        // drain final h0 stores (incl. step 511)
        if (tid == 0)
            __hip_atomic_store(flagp, 512, __ATOMIC_RELAXED,
                               __HIP_MEMORY_SCOPE_AGENT);
    }
}

// ---------------------------------------------------------------------------
extern "C" void kernel_launch(void* const* d_in, const int* in_sizes, int n_in,
                              void* d_out, int out_size, void* d_ws, size_t ws_size,
                              hipStream_t stream)
{
    const float* x  = (const float*)d_in[0];
    const float* W0 = (const float*)d_in[1];
    const float* U0 = (const float*)d_in[2];
    const float* b0 = (const float*)d_in[3];
    const float* W1 = (const float*)d_in[4];
    const float* U1 = (const float*)d_in[5];
    const float* b1 = (const float*)d_in[6];
    float* out = (float*)d_out;

    char* ws = (char*)d_ws;
    __bf16* frags = (__bf16*)ws;                 // 2 * 98304 bf16 = 393,216 B
    int*    flags = (int*)(ws + 393216);         // 16 pairs x 64 B = 1024 B
    // h0 at ws + 448 KiB if it fits, else alias d_out (pipeline-safe: consumer
    // reads slot t+2 strictly before overwriting slot t).
    float* h0;
    const size_t need = 458752 + 67108864;
    if (ws_size >= need) h0 = (float*)(ws + 458752);
    else                 h0 = out;

    prep_frags<<<48, 512, 0, stream>>>(W0, U0, W1, U1, frags, flags);
    gru_pipe<<<32, 512, 0, stream>>>(x, frags, b0, b1, h0, out, flags);
}

// Round 5
// 552.480 us; speedup vs baseline: 2.6936x; 1.0428x over previous
//
#include <hip/hip_runtime.h>
#include <cstdint>
#include <cstddef>

typedef __bf16 bf16x8 __attribute__((ext_vector_type(8)));
typedef __bf16 bf16x4 __attribute__((ext_vector_type(4)));
typedef float  f32x4  __attribute__((ext_vector_type(4)));

#define MFMA16(a,b,c) __builtin_amdgcn_mfma_f32_16x16x32_bf16((a),(b),(c),0,0,0)

// LDS-only barrier: per-step double-buffer handoff needs lgkmcnt(0) only.
// Global stores drained explicitly at publish points (BAR_FULL).
#define BAR_LGKM() __asm__ volatile("s_waitcnt lgkmcnt(0)\n\ts_barrier" ::: "memory")
#define BAR_FULL() __asm__ volatile("s_waitcnt vmcnt(0) lgkmcnt(0)\n\ts_barrier" ::: "memory")

#define L2E  1.4426950408889634f   // log2(e)
#define L2E2 2.8853900817779268f   // 2*log2(e)

// Problem: B=256, T=512, D=H=128, 3H=384. x/out batch stride = 65536 elems.
// 32 blocks: 0..15 layer 0 (producer), 16..31 layer 1 (consumer, lagged).
// h0 crosses XCDs via nt stores/loads + per-pair agent-scope flags.
//
// Round-5 change (overlap MFMA with epilogue VALU): split K=256 into
//   - 12 CRITICAL rec MFMAs: h_{t-1}·U with C-init = carried xp_t registers
//     (same kt-ascending C-chain as the merged version -> bit-identical)
//   - 12 INDEPENDENT MFMAs: xp_{t+2} = x_{t+2}·W from a separately staged
//     LDS x-tile, issued before the epilogue so they drain in the matrix
//     pipe while the epilogue transcendentals run on the VALU.
// xp carries live in named even/odd register sets (unroll-by-2 macro; no
// runtime-indexed vector arrays -> no scratch). LDS: split x/h tiles,
// unpadded [16][128] bf16 with XOR swizzle byte^=((row&7)<<4) (per-lane
// constant offsets, zero per-step address cost).

// ---------------------------------------------------------------------------
// prep_frags: stacked-weight B-frags, K=256 ([W(128) ; U(128)]), + flag init.
// Frag layout (16x16x32): B[k][n], n = lane&15, k = kt*32 + (lane>>4)*8 + j.
// Elem offset = ((ct*8+kt)*64 + lane)*8 + j, ct 0..23 (z:0-7,r:8-15,h:16-23),
// kt 0..7 (kt<4 -> W rows k, kt>=4 -> U rows k-128). Per layer: 98304 bf16.
// Values pre-scaled: L2E for z/r cols (ct<16), L2E2 for h cols (ct>=16).
// ---------------------------------------------------------------------------
__global__ void prep_frags(const float* __restrict__ W0, const float* __restrict__ U0,
                           const float* __restrict__ W1, const float* __restrict__ U1,
                           __bf16* __restrict__ frags, int* __restrict__ flags)
{
    if (blockIdx.x == 0 && threadIdx.x < 16) flags[threadIdx.x * 16] = 0;
    int id = blockIdx.x * 512 + threadIdx.x;      // 0..24575
    int layer = id / 12288;
    int r     = id % 12288;                       // (ct*8+kt)*64 + lane
    int lane = r & 63;
    int ctkt = r >> 6;                            // 0..191
    int kt = ctkt & 7;
    int ct = ctkt >> 3;
    const float* Wsrc = layer ? W1 : W0;
    const float* Usrc = layer ? U1 : U0;
    int n  = ct * 16 + (lane & 15);
    int k0 = kt * 32 + (lane >> 4) * 8;           // never straddles 128
    const float* src = (k0 < 128) ? (Wsrc + (size_t)k0 * 384)
                                  : (Usrc + (size_t)(k0 - 128) * 384);
    const float s = (ct < 16) ? L2E : L2E2;       // z,r vs h columns
    __bf16* dst = frags + (size_t)layer * 98304 + (size_t)r * 8;
#pragma unroll
    for (int j = 0; j < 8; j++)
        dst[j] = (__bf16)(src[(size_t)j * 384 + n] * s);
}

// ---------------------------------------------------------------------------
// gru_pipe: per block 16 batch rows, 512 threads (8 waves, 2/SIMD). Wave w
// owns hidden col j=16w+l15 for all gates. Per step t:
//   rec: az/ar (C-init = xp carry) += h_{t-1}·U ; ahh = h-gate rec part
//   indep: xp_{t+2} = x_{t+2}·W  (hidden under epilogue VALU)
// Producer publishes flag=t every 4th step after a FULL drain: flag F
// asserts h0 steps 0..F-1 are in HBM. Consumer loads h0_{t+4} at step t
// (gated flag >= t+5); prologue loads h0_0..3 (gated flag >= 4).
// h0 may alias out (small-ws fallback): consumer reads slot t+4 strictly
// before overwriting slot t. No __restrict__ on x/h0/out.
// ---------------------------------------------------------------------------
__global__ __launch_bounds__(512, 2) void gru_pipe(
    const float* x, const __bf16* __restrict__ frags,
    const float* __restrict__ b0, const float* __restrict__ b1,
    float* h0, float* out, int* flags)
{
    __shared__ __align__(16) __bf16 xb[2][2048];   // x_{t+2} tiles (ring of 2)
    __shared__ __align__(16) __bf16 hb[2][2048];   // h double buffer

    const int tid  = threadIdx.x;
    const int wave = tid >> 6, lane = tid & 63;
    const int l15  = lane & 15, quad = lane >> 4;
    const int pair  = blockIdx.x & 15;
    const int layer = blockIdx.x >> 4;
    const int B0 = pair * 16;
    int* const flagp = flags + pair * 16;          // one 64B line per pair

    const __bf16* Bf  = frags + (size_t)layer * 98304;
    const float* bias = layer ? b1 : b0;
    const float* xin  = layer ? h0 : x;
    float*       hout = layer ? out : h0;

    // persistent B-frags: W part (kt 0..3) and U part (kt 4..7), pinned so
    // the loads cannot be sunk into the t-loop (round-3/4 lesson).
    bf16x8 bw[3][4], bu[3][4];
#pragma unroll
    for (int g = 0; g < 3; g++) {
        int ct = 8 * g + wave;
#pragma unroll
        for (int kt = 0; kt < 4; kt++) {
            bw[g][kt] = *(const bf16x8*)(Bf + (size_t)((ct * 8 + kt) * 64 + lane) * 8);
            bu[g][kt] = *(const bf16x8*)(Bf + (size_t)((ct * 8 + kt + 4) * 64 + lane) * 8);
            __asm__ volatile("" : "+v"(bw[g][kt]));
            __asm__ volatile("" : "+v"(bu[g][kt]));
        }
    }

    const int j = wave * 16 + l15;
    const float bz  = (bias[j]       + bias[384 + j]) * L2E;
    const float br  = (bias[128 + j] + bias[512 + j]) * L2E;
    const float bxh = bias[256 + j] * L2E2;
    const float brh = bias[640 + j] * L2E2;

    // staging map: 512 threads cover 16 rows x 128 cols (4 floats each)
    const int srow = tid >> 5;
    const float* px = xin + (size_t)(B0 + srow) * 65536 + (tid & 31) * 4;
    // swizzled staging byte offset (8B store; XOR bits 4..6 stay row-local)
    const int sb = (srow * 256 + (tid & 31) * 8) ^ ((srow & 7) << 4);

    // A-frag byte offsets: row l15, k-cols quad*8 + kt*32 (bf16) -> bytes
    const int swz = (l15 & 7) << 4;
    const int abb = l15 * 256 + quad * 16;
    const int ao0 = (abb      ) ^ swz;
    const int ao1 = (abb +  64) ^ swz;
    const int ao2 = (abb + 128) ^ swz;
    const int ao3 = (abb + 192) ^ swz;
    // h-write byte offsets (scalar bf16, row = quad*4+r, col j)
    int hw_[4];
#pragma unroll
    for (int r = 0; r < 4; r++) {
        int row = quad * 4 + r;
        hw_[r] = (row * 256 + j * 2) ^ ((row & 7) << 4);
    }

    const size_t obase = (size_t)(B0 + quad * 4) * 65536 + j;

    int known = 0;
    if (layer) {                 // prologue touches h0 steps 0..3
        while (known < 4) {
            __builtin_amdgcn_s_sleep(4);
            known = __hip_atomic_load(flagp, __ATOMIC_RELAXED,
                                      __HIP_MEMORY_SCOPE_AGENT);
        }
    }

#define LOADX(p) (layer ? __builtin_nontemporal_load((const f32x4*)(p)) \
                        : *(const f32x4*)(p))
#define PACKST(buf, v) do { bf16x4 hv_;                                  \
        hv_.x = (__bf16)(v)[0]; hv_.y = (__bf16)(v)[1];                  \
        hv_.z = (__bf16)(v)[2]; hv_.w = (__bf16)(v)[3];                  \
        *(bf16x4*)((char*)&(buf)[0] + sb) = hv_; } while (0)

    const f32x4 zv = {0.f, 0.f, 0.f, 0.f};

    // ---- prologue: stage x_0,x_1; zero h; compute xp_0, xp_1; stage x_2 ----
    {
        f32x4 v0 = LOADX(px);
        f32x4 v1 = LOADX(px + 128);
        PACKST(xb[0], v0);
        PACKST(xb[1], v1);
        ((uint64_t*)&hb[0][0])[tid] = 0ull;        // 4096 B = 512 x 8B
    }
    __syncthreads();

    f32x4 xpzE = zv, xprE = zv, xphE = zv;         // xp_0 (even set)
    f32x4 xpzO = zv, xprO = zv, xphO = zv;         // xp_1 (odd set)
    {
        bf16x8 Ax0 = *(const bf16x8*)((const char*)&xb[0][0] + ao0);
        bf16x8 Ax1 = *(const bf16x8*)((const char*)&xb[0][0] + ao1);
        bf16x8 Ax2 = *(const bf16x8*)((const char*)&xb[0][0] + ao2);
        bf16x8 Ax3 = *(const bf16x8*)((const char*)&xb[0][0] + ao3);
        xpzE = MFMA16(Ax0, bw[0][0], xpzE); xprE = MFMA16(Ax0, bw[1][0], xprE); xphE = MFMA16(Ax0, bw[2][0], xphE);
        xpzE = MFMA16(Ax1, bw[0][1], xpzE); xprE = MFMA16(Ax1, bw[1][1], xprE); xphE = MFMA16(Ax1, bw[2][1], xphE);
        xpzE = MFMA16(Ax2, bw[0][2], xpzE); xprE = MFMA16(Ax2, bw[1][2], xprE); xphE = MFMA16(Ax2, bw[2][2], xphE);
        xpzE = MFMA16(Ax3, bw[0][3], xpzE); xprE = MFMA16(Ax3, bw[1][3], xprE); xphE = MFMA16(Ax3, bw[2][3], xphE);
    }
    {
        bf16x8 Ax0 = *(const bf16x8*)((const char*)&xb[1][0] + ao0);
        bf16x8 Ax1 = *(const bf16x8*)((const char*)&xb[1][0] + ao1);
        bf16x8 Ax2 = *(const bf16x8*)((const char*)&xb[1][0] + ao2);
        bf16x8 Ax3 = *(const bf16x8*)((const char*)&xb[1][0] + ao3);
        xpzO = MFMA16(Ax0, bw[0][0], xpzO); xprO = MFMA16(Ax0, bw[1][0], xprO); xphO = MFMA16(Ax0, bw[2][0], xphO);
        xpzO = MFMA16(Ax1, bw[0][1], xpzO); xprO = MFMA16(Ax1, bw[1][1], xprO); xphO = MFMA16(Ax1, bw[2][1], xphO);
        xpzO = MFMA16(Ax2, bw[0][2], xpzO); xprO = MFMA16(Ax2, bw[1][2], xprO); xphO = MFMA16(Ax2, bw[2][2], xphO);
        xpzO = MFMA16(Ax3, bw[0][3], xpzO); xprO = MFMA16(Ax3, bw[1][3], xprO); xphO = MFMA16(Ax3, bw[2][3], xphO);
    }
    __syncthreads();                                // all reads of xb[0] done
    {
        f32x4 v2 = LOADX(px + 256);                 // x_2 -> slot 0
        PACKST(xb[0], v2);
    }
    f32x4 vc = LOADX(px + 384);                     // x_3 (staged at t=0)
    float hold[4] = {0.f, 0.f, 0.f, 0.f};
    __syncthreads();

    // Loop invariant at step t: hb[t&1] = h_{t-1}; xb[t&1] = x_{t+2};
    // xp carry (parity set) = xp_t; vc = x_{t+3}.
#define GRU_BODY(T, S, xpz, xpr, xph)                                         \
    {                                                                         \
        const int t_ = (T);                                                   \
        if (layer) {                                /* gate h0_{t+4} load */  \
            int need = t_ + 5; if (need > 512) need = 512;                    \
            while (known < need) {                                            \
                __builtin_amdgcn_s_sleep(4);                                  \
                known = __hip_atomic_load(flagp, __ATOMIC_RELAXED,            \
                                          __HIP_MEMORY_SCOPE_AGENT);          \
            }                                                                 \
        }                                                                     \
        int t4_ = t_ + 4; if (t4_ > 511) t4_ = 511;                           \
        f32x4 vn = LOADX(px + (size_t)t4_ * 128);                             \
        bf16x8 Ah0 = *(const bf16x8*)((const char*)&hb[S][0] + ao0);          \
        bf16x8 Ah1 = *(const bf16x8*)((const char*)&hb[S][0] + ao1);          \
        bf16x8 Ah2 = *(const bf16x8*)((const char*)&hb[S][0] + ao2);          \
        bf16x8 Ah3 = *(const bf16x8*)((const char*)&hb[S][0] + ao3);          \
        f32x4 az = xpz, ar = xpr, ahh = zv;                                   \
        __builtin_amdgcn_s_setprio(1);                                        \
        az = MFMA16(Ah0, bu[0][0], az); ar = MFMA16(Ah0, bu[1][0], ar);       \
        ahh = MFMA16(Ah0, bu[2][0], ahh);                                     \
        az = MFMA16(Ah1, bu[0][1], az); ar = MFMA16(Ah1, bu[1][1], ar);       \
        ahh = MFMA16(Ah1, bu[2][1], ahh);                                     \
        az = MFMA16(Ah2, bu[0][2], az); ar = MFMA16(Ah2, bu[1][2], ar);       \
        ahh = MFMA16(Ah2, bu[2][2], ahh);                                     \
        az = MFMA16(Ah3, bu[0][3], az); ar = MFMA16(Ah3, bu[1][3], ar);       \
        ahh = MFMA16(Ah3, bu[2][3], ahh);                                     \
        /* independent: xp_{t+2} = x_{t+2}*W, drains under the epilogue */    \
        bf16x8 Ax0 = *(const bf16x8*)((const char*)&xb[S][0] + ao0);          \
        bf16x8 Ax1 = *(const bf16x8*)((const char*)&xb[S][0] + ao1);          \
        bf16x8 Ax2 = *(const bf16x8*)((const char*)&xb[S][0] + ao2);          \
        bf16x8 Ax3 = *(const bf16x8*)((const char*)&xb[S][0] + ao3);          \
        f32x4 xhc = xph;                          /* xp_t h-part for epi */   \
        xpz = zv; xpr = zv; xph = zv;                                         \
        xpz = MFMA16(Ax0, bw[0][0], xpz); xpr = MFMA16(Ax0, bw[1][0], xpr);   \
        xph = MFMA16(Ax0, bw[2][0], xph);                                     \
        xpz = MFMA16(Ax1, bw[0][1], xpz); xpr = MFMA16(Ax1, bw[1][1], xpr);   \
        xph = MFMA16(Ax1, bw[2][1], xph);                                     \
        xpz = MFMA16(Ax2, bw[0][2], xpz); xpr = MFMA16(Ax2, bw[1][2], xpr);   \
        xph = MFMA16(Ax2, bw[2][2], xph);                                     \
        xpz = MFMA16(Ax3, bw[0][3], xpz); xpr = MFMA16(Ax3, bw[1][3], xpr);   \
        xph = MFMA16(Ax3, bw[2][3], xph);                                     \
        __builtin_amdgcn_s_setprio(0);                                        \
        /* epilogue (pre-scaled by log2e/2log2e -> raw 2^x) */                \
        float hnew[4];                                                        \
        _Pragma("unroll")                                                     \
        for (int r = 0; r < 4; r++) {                                         \
            float z  = __builtin_amdgcn_rcpf(                                 \
                           1.f + __builtin_amdgcn_exp2f(-(az[r] + bz)));      \
            float rg = __builtin_amdgcn_rcpf(                                 \
                           1.f + __builtin_amdgcn_exp2f(-(ar[r] + br)));      \
            float hp = (xhc[r] + bxh) + rg * (ahh[r] + brh);                  \
            float e2 = __builtin_amdgcn_exp2f(hp);                            \
            float th = 1.f - 2.f * __builtin_amdgcn_rcpf(e2 + 1.f);           \
            hnew[r] = th + z * (hold[r] - th);                                \
            hold[r] = hnew[r];                                                \
        }                                                                     \
        /* stage x_{t+3} and h_t into the opposite buffers */                 \
        PACKST(xb[(S) ^ 1], vc);                                              \
        _Pragma("unroll")                                                     \
        for (int r = 0; r < 4; r++)                                           \
            *(__bf16*)((char*)&hb[(S) ^ 1][0] + hw_[r]) = (__bf16)hnew[r];    \
        if (layer == 0 && (t_ & 3) == 3) {                                    \
            BAR_FULL();               /* h0 stores of steps <= t-1 in HBM */  \
            if (tid == 0)                                                     \
                __hip_atomic_store(flagp, t_, __ATOMIC_RELAXED,               \
                                   __HIP_MEMORY_SCOPE_AGENT);                 \
        } else {                                                              \
            BAR_LGKM();                                                       \
        }                                                                     \
        if (layer == 0) {                                                     \
            _Pragma("unroll")                                                 \
            for (int r = 0; r < 4; r++)                                       \
                __builtin_nontemporal_store(hnew[r],                          \
                    hout + obase + (size_t)r * 65536 + (size_t)t_ * 128);     \
        } else {                                                              \
            _Pragma("unroll")                                                 \
            for (int r = 0; r < 4; r++)                                       \
                hout[obase + (size_t)r * 65536 + (size_t)t_ * 128] = hnew[r]; \
        }                                                                     \
        vc = vn;                                                              \
    }

    for (int it = 0; it < 256; ++it) {
        GRU_BODY(2 * it,     0, xpzE, xprE, xphE);
        GRU_BODY(2 * it + 1, 1, xpzO, xprO, xphO);
    }
#undef GRU_BODY
#undef PACKST
#undef LOADX

    if (layer == 0) {
        BAR_FULL();        // drain final h0 stores (incl. step 511)
        if (tid == 0)
            __hip_atomic_store(flagp, 512, __ATOMIC_RELAXED,
                               __HIP_MEMORY_SCOPE_AGENT);
    }
}

// ---------------------------------------------------------------------------
extern "C" void kernel_launch(void* const* d_in, const int* in_sizes, int n_in,
                              void* d_out, int out_size, void* d_ws, size_t ws_size,
                              hipStream_t stream)
{
    const float* x  = (const float*)d_in[0];
    const float* W0 = (const float*)d_in[1];
    const float* U0 = (const float*)d_in[2];
    const float* b0 = (const float*)d_in[3];
    const float* W1 = (const float*)d_in[4];
    const float* U1 = (const float*)d_in[5];
    const float* b1 = (const float*)d_in[6];
    float* out = (float*)d_out;

    char* ws = (char*)d_ws;
    __bf16* frags = (__bf16*)ws;                 // 2 * 98304 bf16 = 393,216 B
    int*    flags = (int*)(ws + 393216);         // 16 pairs x 64 B = 1024 B
    // h0 at ws + 448 KiB if it fits, else alias d_out (pipeline-safe: consumer
    // reads slot t+4 strictly before overwriting slot t).
    float* h0;
    const size_t need = 458752 + 67108864;
    if (ws_size >= need) h0 = (float*)(ws + 458752);
    else                 h0 = out;

    prep_frags<<<48, 512, 0, stream>>>(W0, U0, W1, U1, frags, flags);
    gru_pipe<<<32, 512, 0, stream>>>(x, frags, b0, b1, h0, out, flags);
}